// Round 11
// baseline (251.135 us; speedup 1.0000x reference)
//
#include <hip/hip_runtime.h>
#include <hip/hip_bf16.h>

#define D 128            // D_IN == D_OUT == 128
#define BROWS 128        // nodes per coarse bucket
#define BSHIFT 7         // log2(BROWS)
#define BIN_CHUNK 16384  // edges per binning block (512 threads)
#define SORT_CAP 6144    // max edges sorted in LDS (mean ~4092, sigma ~64)

typedef __attribute__((ext_vector_type(8))) short short8;   // 8 bf16 (4 VGPR)
typedef __attribute__((ext_vector_type(4))) float f32x4;    // MFMA acc

static __device__ inline unsigned short f2bf(float x) {
    unsigned int u = __float_as_uint(x);
    return (unsigned short)((u + 0x7FFFu + ((u >> 16) & 1u)) >> 16);  // RNE
}
static __device__ inline float bf2f(unsigned int h16) {
    return __uint_as_float(h16 << 16);
}

// ---------------------------------------------------------------------------
// Fused: blocks [0,G) do S = X@W via v_mfma_f32_16x16x32_bf16 (verified
// R7-R9); blocks [G,G+256) do the coarse bucket histogram (LDS-aggregated,
// memory-bound -> hides under the compute-bound GEMM in the same dispatch).
// bhist's h[1024] aliases the gemm smem (block-uniform branch).
// ---------------------------------------------------------------------------
__global__ __launch_bounds__(256) void gemm_hist_kernel(const float* __restrict__ X,
                                                        const float* __restrict__ W,
                                                        unsigned short* __restrict__ Sb,
                                                        int n_rows,
                                                        const int* __restrict__ erow,
                                                        int* __restrict__ cnt,
                                                        int n_edges, int nb,
                                                        int gemm_blocks) {
    __shared__ unsigned char smem[49152];   // gemm: Xs/C | Wt ; bhist: h[1024]

    const int tid = threadIdx.x;

    if ((int)blockIdx.x >= gemm_blocks) {
        // ---------------- bhist path ----------------
        int* h = (int*)smem;
        const int bid = blockIdx.x - gemm_blocks;        // 0..255
        for (int i = tid; i < nb; i += 256) h[i] = 0;
        __syncthreads();
        int i = bid * 256 + tid;
        const int stride = 256 * 256;
        for (; i < n_edges; i += stride) atomicAdd(&h[erow[i] >> BSHIFT], 1);
        __syncthreads();
        for (int b = tid; b < nb; b += 256)
            if (h[b]) atomicAdd(&cnt[b], h[b]);
        return;
    }

    // ---------------- gemm path ----------------
    const int row0 = blockIdx.x * 64;

    #pragma unroll
    for (int i = 0; i < 8; ++i) {
        int idx = tid + i * 256;            // 2048 float4 units
        int r = idx >> 5, c4 = idx & 31;
        float4 v = make_float4(0.f, 0.f, 0.f, 0.f);
        if (row0 + r < n_rows) v = ((const float4*)(X + (size_t)(row0 + r) * D))[c4];
        uint2 pk;
        pk.x = (unsigned)f2bf(v.x) | ((unsigned)f2bf(v.y) << 16);
        pk.y = (unsigned)f2bf(v.z) | ((unsigned)f2bf(v.w) << 16);
        *(uint2*)(smem + r * 256 + ((c4 * 8) ^ ((r & 7) << 4))) = pk;
    }
    #pragma unroll
    for (int i = 0; i < 8; ++i) {
        int id = tid + i * 256;             // 2048 tasks: (n, 8-k chunk)
        int n = id & 127, kc = id >> 7;     // kc in [0,16)
        float f0 = W[(size_t)(kc * 8 + 0) * D + n];
        float f1 = W[(size_t)(kc * 8 + 1) * D + n];
        float f2 = W[(size_t)(kc * 8 + 2) * D + n];
        float f3 = W[(size_t)(kc * 8 + 3) * D + n];
        float f4 = W[(size_t)(kc * 8 + 4) * D + n];
        float f5 = W[(size_t)(kc * 8 + 5) * D + n];
        float f6 = W[(size_t)(kc * 8 + 6) * D + n];
        float f7 = W[(size_t)(kc * 8 + 7) * D + n];
        unsigned pk0 = (unsigned)f2bf(f0) | ((unsigned)f2bf(f1) << 16);
        unsigned pk1 = (unsigned)f2bf(f2) | ((unsigned)f2bf(f3) << 16);
        unsigned pk2 = (unsigned)f2bf(f4) | ((unsigned)f2bf(f5) << 16);
        unsigned pk3 = (unsigned)f2bf(f6) | ((unsigned)f2bf(f7) << 16);
        *(uint4*)(smem + 16384 + n * 256 + ((kc * 16) ^ ((n & 7) << 4))) =
            make_uint4(pk0, pk1, pk2, pk3);
    }
    __syncthreads();

    const int wv  = __builtin_amdgcn_readfirstlane(tid >> 6);
    const int l15 = tid & 15;
    const int lhi = (tid & 63) >> 4;

    f32x4 acc[4][2];
    #pragma unroll
    for (int m = 0; m < 4; ++m)
        #pragma unroll
        for (int j = 0; j < 2; ++j) acc[m][j] = (f32x4){0.f, 0.f, 0.f, 0.f};

    #pragma unroll
    for (int ks = 0; ks < 4; ++ks) {        // K = 4 x 32
        const int kb = ks * 64 + lhi * 16;
        short8 a[4], b[2];
        #pragma unroll
        for (int m = 0; m < 4; ++m) {
            int r = m * 16 + l15;
            a[m] = *(const short8*)(smem + r * 256 + (kb ^ ((r & 7) << 4)));
        }
        #pragma unroll
        for (int j = 0; j < 2; ++j) {
            int n = wv * 32 + j * 16 + l15;
            b[j] = *(const short8*)(smem + 16384 + n * 256 + (kb ^ ((n & 7) << 4)));
        }
        #pragma unroll
        for (int m = 0; m < 4; ++m)
            #pragma unroll
            for (int j = 0; j < 2; ++j)
                acc[m][j] = __builtin_amdgcn_mfma_f32_16x16x32_bf16(a[m], b[j],
                                                                   acc[m][j], 0, 0, 0);
    }
    __syncthreads();

    #pragma unroll
    for (int m = 0; m < 4; ++m)
        #pragma unroll
        for (int j = 0; j < 2; ++j)
            #pragma unroll
            for (int r = 0; r < 4; ++r) {
                int row = m * 16 + lhi * 4 + r;
                int col = wv * 32 + j * 16 + l15;
                *(unsigned short*)(smem + row * 256 + ((col * 2) ^ ((row & 7) << 4))) =
                    f2bf(acc[m][j][r]);
            }
    __syncthreads();
    // 64x128 bf16 tile = 1024 sixteen-byte units -> exactly 4 iterations.
    #pragma unroll
    for (int i = 0; i < 4; ++i) {
        int idx = tid + i * 256;            // 0..1023
        int r = idx >> 4, kb = (idx & 15) * 16;
        uint4 v = *(const uint4*)(smem + r * 256 + (kb ^ ((r & 7) << 4)));
        int row = row0 + r;
        if (row < n_rows)
            *(uint4*)((unsigned char*)Sb + (size_t)row * 256 + kb) = v;
    }
}

// single block: exclusive scan of cnt -> bstart (stable) and curm (cursors)
__global__ __launch_bounds__(1024) void bscan_kernel(const int* __restrict__ cnt,
                                                     int* __restrict__ bstart,
                                                     int* __restrict__ curm, int nb) {
    __shared__ int s[1024];
    int tid = threadIdx.x;
    int v = (tid < nb) ? cnt[tid] : 0;
    s[tid] = v;
    __syncthreads();
    for (int d = 1; d < 1024; d <<= 1) {
        int t = (tid >= d) ? s[tid - d] : 0;
        __syncthreads();
        s[tid] += t;
        __syncthreads();
    }
    if (tid < nb) {
        int e = s[tid] - v;   // exclusive
        bstart[tid] = e;
        curm[tid]   = e;
    }
}

// ---------------------------------------------------------------------------
// Binning: 512-thread blocks, BIN_CHUNK edges each; one contiguous range
// reservation per (block,bucket). Packed edge: x=(localrow<<25)|col, y=w.
// ---------------------------------------------------------------------------
__global__ __launch_bounds__(512) void bin_kernel(const int* __restrict__ erow,
                                                  const int* __restrict__ ecol,
                                                  const float* __restrict__ ew,
                                                  int* __restrict__ curm,
                                                  int2* __restrict__ binned,
                                                  int n_edges, int nb) {
    __shared__ int h[1024];
    __shared__ int base[1024];
    const int c0  = blockIdx.x * BIN_CHUNK;
    const int tid = threadIdx.x;
    for (int i = tid; i < nb; i += 512) h[i] = 0;
    __syncthreads();
    for (int k = 0; k < BIN_CHUNK; k += 512) {
        int e = c0 + k + tid;
        if (e < n_edges) atomicAdd(&h[erow[e] >> BSHIFT], 1);
    }
    __syncthreads();
    for (int b = tid; b < nb; b += 512) {
        int c = h[b];
        if (c) base[b] = atomicAdd(&curm[b], c);
        h[b] = 0;   // reuse as local cursor
    }
    __syncthreads();
    for (int k = 0; k < BIN_CHUNK; k += 512) {
        int e = c0 + k + tid;
        if (e < n_edges) {
            int row = erow[e];
            int b = row >> BSHIFT;
            int pos = base[b] + atomicAdd(&h[b], 1);
            int2 p;
            p.x = (int)(((unsigned)(row & (BROWS - 1)) << 25) | (unsigned)ecol[e]);
            p.y = __float_as_int(ew[e]);
            binned[pos] = p;
        }
    }
}

// ---------------------------------------------------------------------------
// Fused sort+SpMM: one block (512 thr, 8 waves) per bucket.
//  pass 1: LDS hist of bucket edges; scan -> per-node starts
//  pass 2: re-read edges (L2-hot), scatter into LDS `staged` SORTED
//  pass 3: wave w computes nodes w*16..+15: gather Sb rows per staged edge,
//          register-accumulate, bias fused, single out write. No global
//          sorted-edge array, no offs array, no extra dispatch.
// Nodes with 0 edges still get out=bias. Overflow bucket (>SORT_CAP, ~30
// sigma): bias-init rows then streamed global atomics (block owns its rows).
// ---------------------------------------------------------------------------
__global__ __launch_bounds__(512) void sort_spmm_kernel(const int* __restrict__ cnt,
                                                        const int* __restrict__ bstart,
                                                        const int2* __restrict__ binned,
                                                        const unsigned short* __restrict__ Sb,
                                                        const float* __restrict__ bias,
                                                        float* __restrict__ out,
                                                        int n_nodes) {
    __shared__ int  lhist[BROWS];
    __shared__ int  lstart[BROWS];
    __shared__ int  lcur[BROWS];
    __shared__ int2 staged[SORT_CAP];   // 48 KB

    const int b    = blockIdx.x;
    const int bs   = bstart[b];
    const int cb   = cnt[b];
    const int row0 = b * BROWS;
    const int tid  = threadIdx.x;
    const int w    = tid >> 6;
    const int lane = tid & 63;
    const unsigned* Su = (const unsigned*)Sb;   // 64 dwords per Sb row

    if (tid < BROWS) lhist[tid] = 0;
    __syncthreads();

    if (cb <= SORT_CAP) {
        // pass 1: histogram
        for (int i = tid; i < cb; i += 512)
            atomicAdd(&lhist[(unsigned)binned[bs + i].x >> 25], 1);
        __syncthreads();
        // inclusive Hillis-Steele scan over 128 bins
        if (tid < BROWS) lstart[tid] = lhist[tid];
        __syncthreads();
        for (int d = 1; d < BROWS; d <<= 1) {
            int t = 0;
            if (tid < BROWS && tid >= d) t = lstart[tid - d];
            __syncthreads();
            if (tid < BROWS) lstart[tid] += t;
            __syncthreads();
        }
        if (tid < BROWS) {
            int excl = lstart[tid] - lhist[tid];
            lstart[tid] = excl;
            lcur[tid]   = excl;
        }
        __syncthreads();
        // pass 2: re-read (L2-hot) and scatter into LDS sorted order
        for (int i = tid; i < cb; i += 512) {
            int2 p = binned[bs + i];
            int pos = atomicAdd(&lcur[(unsigned)p.x >> 25], 1);
            staged[pos] = make_int2(p.x & 0x1FFFFFF, p.y);
        }
        __syncthreads();
        // pass 3: SpMM — wave w handles 16 consecutive nodes
        float2 b2 = ((const float2*)bias)[lane];
        #pragma unroll 1
        for (int k = 0; k < 16; ++k) {
            int ln   = w * 16 + k;
            int node = row0 + ln;
            if (node >= n_nodes) break;
            int es = lstart[ln];
            int cn = lhist[ln];
            float ax = b2.x, ay = b2.y;
            int e = 0;
            for (; e + 7 < cn; e += 8) {
                int2 p[8];
                #pragma unroll
                for (int j = 0; j < 8; ++j) p[j] = staged[es + e + j];
                unsigned sv[8];
                #pragma unroll
                for (int j = 0; j < 8; ++j) sv[j] = Su[(size_t)p[j].x * 64 + lane];
                #pragma unroll
                for (int j = 0; j < 8; ++j) {
                    float wt = __int_as_float(p[j].y);
                    ax += wt * bf2f(sv[j] & 0xFFFFu);
                    ay += wt * bf2f(sv[j] >> 16);
                }
            }
            for (; e < cn; ++e) {
                int2 p = staged[es + e];
                unsigned s = Su[(size_t)p.x * 64 + lane];
                float wt = __int_as_float(p.y);
                ax += wt * bf2f(s & 0xFFFFu);
                ay += wt * bf2f(s >> 16);
            }
            float2 o; o.x = ax; o.y = ay;
            ((float2*)(out + (size_t)node * D))[lane] = o;
        }
    } else {
        // ---- overflow (statistically unreachable): bias-init + atomics ----
        const int nrows = min(BROWS, n_nodes - row0);
        for (int i = tid; i < nrows * 32; i += 512) {   // 32 float4 per row
            int r = i >> 5, c = i & 31;
            ((float4*)(out + (size_t)(row0 + r) * D))[c] = ((const float4*)bias)[c];
        }
        __syncthreads();
        for (int e = w; e < cb; e += 8) {
            int2 p = binned[bs + e];
            int lr  = (unsigned)p.x >> 25;
            int col = p.x & 0x1FFFFFF;
            unsigned sv = Su[(size_t)col * 64 + lane];
            float wt = __int_as_float(p.y);
            float* op = out + (size_t)(row0 + lr) * D + lane * 2;
            unsafeAtomicAdd(op,     wt * bf2f(sv & 0xFFFFu));
            unsafeAtomicAdd(op + 1, wt * bf2f(sv >> 16));
        }
    }
}

// ---------------------------------------------------------------------------
// Fallback path (ws too small / too many buckets): fp32 S + output atomics.
// ---------------------------------------------------------------------------
__global__ __launch_bounds__(256) void gemm_f32_kernel(const float* __restrict__ X,
                                                       const float* __restrict__ W,
                                                       float* __restrict__ S,
                                                       int n_rows) {
    __shared__ float Ws[D * D];
    __shared__ float Xs[64 * 132];
    const int tid  = threadIdx.x;
    const int row0 = blockIdx.x * 64;
    #pragma unroll
    for (int i = 0; i < 16; ++i) {
        int idx = tid + i * 256;
        ((float4*)Ws)[idx] = ((const float4*)W)[idx];
    }
    #pragma unroll
    for (int i = 0; i < 8; ++i) {
        int idx = tid + i * 256;
        int r = idx >> 5, c4 = idx & 31;
        if (row0 + r < n_rows) {
            float4 v = ((const float4*)(X + (size_t)(row0 + r) * D))[c4];
            *((float4*)&Xs[r * 132 + c4 * 4]) = v;
        }
    }
    __syncthreads();
    const int cg = tid & 15, rg = tid >> 4;
    const int r0 = rg * 4, c0 = cg * 4, c1 = 64 + cg * 4;
    float acc[4][8];
    #pragma unroll
    for (int r = 0; r < 4; ++r)
        #pragma unroll
        for (int c = 0; c < 8; ++c) acc[r][c] = 0.f;
    #pragma unroll 4
    for (int k = 0; k < D; ++k) {
        float4 w0 = *((const float4*)&Ws[k * D + c0]);
        float4 w1 = *((const float4*)&Ws[k * D + c1]);
        #pragma unroll
        for (int r = 0; r < 4; ++r) {
            float x = Xs[(r0 + r) * 132 + k];
            acc[r][0] += x * w0.x; acc[r][1] += x * w0.y;
            acc[r][2] += x * w0.z; acc[r][3] += x * w0.w;
            acc[r][4] += x * w1.x; acc[r][5] += x * w1.y;
            acc[r][6] += x * w1.z; acc[r][7] += x * w1.w;
        }
    }
    #pragma unroll
    for (int r = 0; r < 4; ++r) {
        int row = row0 + r0 + r;
        if (row < n_rows) {
            float4 o0 = {acc[r][0], acc[r][1], acc[r][2], acc[r][3]};
            float4 o1 = {acc[r][4], acc[r][5], acc[r][6], acc[r][7]};
            ((float4*)(S + (size_t)row * D))[cg]      = o0;
            ((float4*)(S + (size_t)row * D))[16 + cg] = o1;
        }
    }
}

__global__ __launch_bounds__(256) void init_out_kernel(float* __restrict__ out,
                                                       const float* __restrict__ bias,
                                                       int total4) {
    int idx = blockIdx.x * blockDim.x + threadIdx.x;
    int stride = gridDim.x * blockDim.x;
    for (; idx < total4; idx += stride) {
        float4 b = ((const float4*)bias)[idx & 31];
        ((float4*)out)[idx] = b;
    }
}

__global__ __launch_bounds__(256) void spmm_atomic_kernel(const float* __restrict__ S,
                                                          const int* __restrict__ erow,
                                                          const int* __restrict__ ecol,
                                                          const float* __restrict__ ew,
                                                          float* __restrict__ out,
                                                          int n_edges) {
    const int lane   = threadIdx.x & 63;
    const int wave   = blockIdx.x * (blockDim.x >> 6) + (threadIdx.x >> 6);
    const int nwaves = gridDim.x * (blockDim.x >> 6);
    for (int e = wave; e < n_edges; e += nwaves) {
        int   col = ecol[e];
        int   row = erow[e];
        float w   = ew[e];
        float2 s  = *(((const float2*)(S + (size_t)col * D)) + lane);
        float* op = out + (size_t)row * D + lane * 2;
        unsafeAtomicAdd(op,     w * s.x);
        unsafeAtomicAdd(op + 1, w * s.y);
    }
}

extern "C" void kernel_launch(void* const* d_in, const int* in_sizes, int n_in,
                              void* d_out, int out_size, void* d_ws, size_t ws_size,
                              hipStream_t stream) {
    const float* X    = (const float*)d_in[0];
    const int*   erow = (const int*)  d_in[1];
    const int*   ecol = (const int*)  d_in[2];
    const float* ew   = (const float*)d_in[3];
    const float* W    = (const float*)d_in[4];
    const float* bias = (const float*)d_in[5];
    float* out = (float*)d_out;

    const int n_nodes = in_sizes[0] / D;
    const int n_edges = in_sizes[1];
    const int nb      = (n_nodes + BROWS - 1) / BROWS;   // 782

    // workspace: Sb (bf16) | cnt | bstart | curm | binned
    size_t sb_bytes  = (size_t)n_nodes * D * sizeof(unsigned short);  // 25.6 MB
    size_t cnt_bytes = ((size_t)nb * sizeof(int) + 15) & ~(size_t)15;
    size_t bin_bytes = (size_t)n_edges * sizeof(int2);                // 25.6 MB
    size_t need = sb_bytes + 3 * cnt_bytes + bin_bytes + 64;

    if (ws_size >= need && nb <= 1024) {
        char* p = (char*)d_ws;
        unsigned short* Sb = (unsigned short*)p;  p += sb_bytes;
        int* cnt    = (int*)p;                    p += cnt_bytes;
        int* bstart = (int*)p;                    p += cnt_bytes;
        int* curm   = (int*)p;                    p += cnt_bytes;
        p = (char*)(((uintptr_t)p + 15) & ~(uintptr_t)15);
        int2* binned = (int2*)p;

        const int gemm_blocks = (n_nodes + 63) / 64;
        hipMemsetAsync(cnt, 0, (size_t)nb * sizeof(int), stream);
        gemm_hist_kernel<<<gemm_blocks + 256, 256, 0, stream>>>(
            X, W, Sb, n_nodes, erow, cnt, n_edges, nb, gemm_blocks);
        bscan_kernel<<<1, 1024, 0, stream>>>(cnt, bstart, curm, nb);
        bin_kernel<<<(n_edges + BIN_CHUNK - 1) / BIN_CHUNK, 512, 0, stream>>>(
            erow, ecol, ew, curm, binned, n_edges, nb);
        sort_spmm_kernel<<<nb, 512, 0, stream>>>(cnt, bstart, binned, Sb, bias,
                                                 out, n_nodes);
    } else {
        float* S = (float*)d_ws;
        gemm_f32_kernel<<<(n_nodes + 63) / 64, 256, 0, stream>>>(X, W, S, n_nodes);
        init_out_kernel<<<2048, 256, 0, stream>>>(out, bias, n_nodes * (D / 4));
        spmm_atomic_kernel<<<2048, 256, 0, stream>>>(S, erow, ecol, ew, out, n_edges);
    }
}

// Round 12
// 245.248 us; speedup vs baseline: 1.0240x; 1.0240x over previous
//
#include <hip/hip_runtime.h>
#include <hip/hip_bf16.h>

#define D 128            // D_IN == D_OUT == 128
#define BROWS 128        // nodes per coarse bucket
#define BSHIFT 7         // log2(BROWS)
#define BIN_CHUNK 16384  // edges per binning block
#define SORT_CAP 6144    // max edges sorted in LDS (mean ~4092, sigma ~64)

typedef __attribute__((ext_vector_type(8))) short short8;   // 8 bf16 (4 VGPR)
typedef __attribute__((ext_vector_type(4))) float f32x4;    // MFMA acc

static __device__ inline unsigned short f2bf(float x) {
    unsigned int u = __float_as_uint(x);
    return (unsigned short)((u + 0x7FFFu + ((u >> 16) & 1u)) >> 16);  // RNE
}
static __device__ inline float bf2f(unsigned int h16) {
    return __uint_as_float(h16 << 16);
}

// ---------------------------------------------------------------------------
// Coarse bucket histogram: LDS-aggregated, one global atomic per bucket/block.
// ---------------------------------------------------------------------------
__global__ __launch_bounds__(256) void bhist_kernel(const int* __restrict__ erow,
                                                    int* __restrict__ cnt,
                                                    int n_edges, int nb) {
    __shared__ int h[1024];
    for (int i = threadIdx.x; i < nb; i += 256) h[i] = 0;
    __syncthreads();
    int i = blockIdx.x * blockDim.x + threadIdx.x;
    int stride = gridDim.x * blockDim.x;
    for (; i < n_edges; i += stride) atomicAdd(&h[erow[i] >> BSHIFT], 1);
    __syncthreads();
    for (int b = threadIdx.x; b < nb; b += 256)
        if (h[b]) atomicAdd(&cnt[b], h[b]);
}

// single block: exclusive scan of cnt -> bstart (stable) and curm (cursors)
__global__ __launch_bounds__(1024) void bscan_kernel(const int* __restrict__ cnt,
                                                     int* __restrict__ bstart,
                                                     int* __restrict__ curm, int nb) {
    __shared__ int s[1024];
    int tid = threadIdx.x;
    int v = (tid < nb) ? cnt[tid] : 0;
    s[tid] = v;
    __syncthreads();
    for (int d = 1; d < 1024; d <<= 1) {
        int t = (tid >= d) ? s[tid - d] : 0;
        __syncthreads();
        s[tid] += t;
        __syncthreads();
    }
    if (tid < nb) {
        int e = s[tid] - v;   // exclusive
        bstart[tid] = e;
        curm[tid]   = e;
    }
}

// ---------------------------------------------------------------------------
// Fused dispatch: blocks [0,G) run the MFMA GEMM (verified R7-R10); blocks
// [G,G+nbin) run the binning pass (memory-bound -> hides under the GEMM).
// The two parts touch disjoint data; bin's h/base alias the gemm smem.
// GEMM: 64x128 tile, K=128 one LDS pass, 16B-XOR swizzle, C via LDS bounce.
// BIN: reserve one contiguous range per (block,bucket) (1 atomic each),
// write densely. Packed edge: x=(localrow<<25)|col, y=weight bits.
// ---------------------------------------------------------------------------
__global__ __launch_bounds__(256) void gemm_bin_kernel(const float* __restrict__ X,
                                                       const float* __restrict__ W,
                                                       unsigned short* __restrict__ Sb,
                                                       int n_rows,
                                                       const int* __restrict__ erow,
                                                       const int* __restrict__ ecol,
                                                       const float* __restrict__ ew,
                                                       int* __restrict__ curm,
                                                       int2* __restrict__ binned,
                                                       int n_edges, int nb,
                                                       int gemm_blocks) {
    __shared__ unsigned char smem[49152];   // gemm: Xs/C | Wt ; bin: h|base

    const int tid = threadIdx.x;

    if ((int)blockIdx.x >= gemm_blocks) {
        // ---------------- bin path ----------------
        int* h    = (int*)smem;          // [1024]
        int* base = (int*)(smem + 4096); // [1024]
        const int c0 = (blockIdx.x - gemm_blocks) * BIN_CHUNK;
        for (int i = tid; i < nb; i += 256) h[i] = 0;
        __syncthreads();
        for (int k = 0; k < BIN_CHUNK; k += 256) {
            int e = c0 + k + tid;
            if (e < n_edges) atomicAdd(&h[erow[e] >> BSHIFT], 1);
        }
        __syncthreads();
        for (int b = tid; b < nb; b += 256) {
            int c = h[b];
            if (c) base[b] = atomicAdd(&curm[b], c);
            h[b] = 0;   // reuse as local cursor
        }
        __syncthreads();
        for (int k = 0; k < BIN_CHUNK; k += 256) {
            int e = c0 + k + tid;
            if (e < n_edges) {
                int row = erow[e];
                int b = row >> BSHIFT;
                int pos = base[b] + atomicAdd(&h[b], 1);
                int2 p;
                p.x = (int)(((unsigned)(row & (BROWS - 1)) << 25) | (unsigned)ecol[e]);
                p.y = __float_as_int(ew[e]);
                binned[pos] = p;
            }
        }
        return;
    }

    // ---------------- gemm path ----------------
    const int row0 = blockIdx.x * 64;

    #pragma unroll
    for (int i = 0; i < 8; ++i) {
        int idx = tid + i * 256;            // 2048 float4 units
        int r = idx >> 5, c4 = idx & 31;
        float4 v = make_float4(0.f, 0.f, 0.f, 0.f);
        if (row0 + r < n_rows) v = ((const float4*)(X + (size_t)(row0 + r) * D))[c4];
        uint2 pk;
        pk.x = (unsigned)f2bf(v.x) | ((unsigned)f2bf(v.y) << 16);
        pk.y = (unsigned)f2bf(v.z) | ((unsigned)f2bf(v.w) << 16);
        *(uint2*)(smem + r * 256 + ((c4 * 8) ^ ((r & 7) << 4))) = pk;
    }
    #pragma unroll
    for (int i = 0; i < 8; ++i) {
        int id = tid + i * 256;             // 2048 tasks: (n, 8-k chunk)
        int n = id & 127, kc = id >> 7;     // kc in [0,16)
        float f0 = W[(size_t)(kc * 8 + 0) * D + n];
        float f1 = W[(size_t)(kc * 8 + 1) * D + n];
        float f2 = W[(size_t)(kc * 8 + 2) * D + n];
        float f3 = W[(size_t)(kc * 8 + 3) * D + n];
        float f4 = W[(size_t)(kc * 8 + 4) * D + n];
        float f5 = W[(size_t)(kc * 8 + 5) * D + n];
        float f6 = W[(size_t)(kc * 8 + 6) * D + n];
        float f7 = W[(size_t)(kc * 8 + 7) * D + n];
        unsigned pk0 = (unsigned)f2bf(f0) | ((unsigned)f2bf(f1) << 16);
        unsigned pk1 = (unsigned)f2bf(f2) | ((unsigned)f2bf(f3) << 16);
        unsigned pk2 = (unsigned)f2bf(f4) | ((unsigned)f2bf(f5) << 16);
        unsigned pk3 = (unsigned)f2bf(f6) | ((unsigned)f2bf(f7) << 16);
        *(uint4*)(smem + 16384 + n * 256 + ((kc * 16) ^ ((n & 7) << 4))) =
            make_uint4(pk0, pk1, pk2, pk3);
    }
    __syncthreads();

    const int wv  = __builtin_amdgcn_readfirstlane(tid >> 6);
    const int l15 = tid & 15;
    const int lhi = (tid & 63) >> 4;

    f32x4 acc[4][2];
    #pragma unroll
    for (int m = 0; m < 4; ++m)
        #pragma unroll
        for (int j = 0; j < 2; ++j) acc[m][j] = (f32x4){0.f, 0.f, 0.f, 0.f};

    #pragma unroll
    for (int ks = 0; ks < 4; ++ks) {        // K = 4 x 32
        const int kb = ks * 64 + lhi * 16;
        short8 a[4], b[2];
        #pragma unroll
        for (int m = 0; m < 4; ++m) {
            int r = m * 16 + l15;
            a[m] = *(const short8*)(smem + r * 256 + (kb ^ ((r & 7) << 4)));
        }
        #pragma unroll
        for (int j = 0; j < 2; ++j) {
            int n = wv * 32 + j * 16 + l15;
            b[j] = *(const short8*)(smem + 16384 + n * 256 + (kb ^ ((n & 7) << 4)));
        }
        #pragma unroll
        for (int m = 0; m < 4; ++m)
            #pragma unroll
            for (int j = 0; j < 2; ++j)
                acc[m][j] = __builtin_amdgcn_mfma_f32_16x16x32_bf16(a[m], b[j],
                                                                   acc[m][j], 0, 0, 0);
    }
    __syncthreads();

    #pragma unroll
    for (int m = 0; m < 4; ++m)
        #pragma unroll
        for (int j = 0; j < 2; ++j)
            #pragma unroll
            for (int r = 0; r < 4; ++r) {
                int row = m * 16 + lhi * 4 + r;
                int col = wv * 32 + j * 16 + l15;
                *(unsigned short*)(smem + row * 256 + ((col * 2) ^ ((row & 7) << 4))) =
                    f2bf(acc[m][j][r]);
            }
    __syncthreads();
    // 64x128 bf16 tile = 1024 sixteen-byte units -> exactly 4 iterations.
    #pragma unroll
    for (int i = 0; i < 4; ++i) {
        int idx = tid + i * 256;            // 0..1023
        int r = idx >> 4, kb = (idx & 15) * 16;
        uint4 v = *(const uint4*)(smem + r * 256 + (kb ^ ((r & 7) << 4)));
        int row = row0 + r;
        if (row < n_rows)
            *(uint4*)((unsigned char*)Sb + (size_t)row * 256 + kb) = v;
    }
}

// ---------------------------------------------------------------------------
// Per-bucket counting sort, 2-pass, 512 threads (R9 was 256: LDS caps us at
// 3 blocks/CU either way, so 512thr doubles waves/CU 12->24). Pass 1 reads
// binned once (LDS stage + hist); scan; pass 2 scatters LDS->final global
// slot. Emits per-node offsets. Overflow (>SORT_CAP) bounces via aux.
// ---------------------------------------------------------------------------
__global__ __launch_bounds__(512) void csr_sort_kernel(const int* __restrict__ cnt,
                                                       const int* __restrict__ bstart,
                                                       int2* __restrict__ binned,
                                                       int2* __restrict__ aux,
                                                       int* __restrict__ offs,
                                                       int n_nodes) {
    __shared__ int  lhist[BROWS];
    __shared__ int  lscan[BROWS];
    __shared__ int  lcur[BROWS];
    __shared__ int2 staged[SORT_CAP];   // 48 KB

    const int b    = blockIdx.x;
    const int bs   = bstart[b];
    const int cb   = cnt[b];
    const int row0 = b * BROWS;
    const int tid  = threadIdx.x;

    if (tid < BROWS) lhist[tid] = 0;
    __syncthreads();

    if (cb <= SORT_CAP) {
        // pass 1: single global read -> LDS stage + LDS hist
        for (int i = tid; i < cb; i += 512) {
            int2 p = binned[bs + i];
            staged[i] = p;
            atomicAdd(&lhist[(unsigned)p.x >> 25], 1);
        }
        __syncthreads();
        // inclusive Hillis-Steele scan over 128 bins
        if (tid < BROWS) lscan[tid] = lhist[tid];
        __syncthreads();
        for (int d = 1; d < BROWS; d <<= 1) {
            int t = 0;
            if (tid < BROWS && tid >= d) t = lscan[tid - d];
            __syncthreads();
            if (tid < BROWS) lscan[tid] += t;
            __syncthreads();
        }
        if (tid < BROWS) {
            int excl = lscan[tid] - lhist[tid];
            lcur[tid] = excl;
            if (row0 + tid < n_nodes) offs[row0 + tid] = bs + excl;
        }
        __syncthreads();
        // pass 2: LDS -> final global position (writes stay within ~32KB)
        for (int i = tid; i < cb; i += 512) {
            int2 p = staged[i];
            int pos = atomicAdd(&lcur[(unsigned)p.x >> 25], 1);
            binned[bs + pos] = make_int2(p.x & 0x1FFFFFF, p.y);
        }
    } else {
        // rare overflow path: 3 global passes via aux
        for (int i = tid; i < cb; i += 512)
            atomicAdd(&lhist[(unsigned)binned[bs + i].x >> 25], 1);
        __syncthreads();
        if (tid < BROWS) lscan[tid] = lhist[tid];
        __syncthreads();
        for (int d = 1; d < BROWS; d <<= 1) {
            int t = 0;
            if (tid < BROWS && tid >= d) t = lscan[tid - d];
            __syncthreads();
            if (tid < BROWS) lscan[tid] += t;
            __syncthreads();
        }
        if (tid < BROWS) {
            int excl = lscan[tid] - lhist[tid];
            lcur[tid] = excl;
            if (row0 + tid < n_nodes) offs[row0 + tid] = bs + excl;
        }
        __syncthreads();
        for (int i = tid; i < cb; i += 512) aux[bs + i] = binned[bs + i];
        __syncthreads();
        for (int i = tid; i < cb; i += 512) {
            int2 p = aux[bs + i];
            int pos = atomicAdd(&lcur[(unsigned)p.x >> 25], 1);
            binned[bs + pos] = make_int2(p.x & 0x1FFFFFF, p.y);
        }
    }
}

// ---------------------------------------------------------------------------
// CSR SpMM (unchanged from R9: 107us @ 74% occ): one wave per node;
// wave-uniform edge stream; lane l gathers bf16x2 at cols 2l,2l+1;
// 8-deep unroll; bias fused; no atomics.
// ---------------------------------------------------------------------------
__global__ __launch_bounds__(256) void spmm_csr_kernel(const unsigned short* __restrict__ Sb,
                                                       const int* __restrict__ offs,
                                                       const int2* __restrict__ edges,
                                                       const float* __restrict__ bias,
                                                       float* __restrict__ out,
                                                       int n_nodes, int n_edges) {
    const int wv   = __builtin_amdgcn_readfirstlane(threadIdx.x >> 6);
    const int node = blockIdx.x * 4 + wv;
    const int lane = threadIdx.x & 63;
    if (node >= n_nodes) return;
    const int start = offs[node];
    const int end   = (node + 1 < n_nodes) ? offs[node + 1] : n_edges;

    const unsigned* Su = (const unsigned*)Sb;   // 64 dwords per row
    float2 b2 = ((const float2*)bias)[lane];
    float ax = b2.x, ay = b2.y;

    int e = start;
    for (; e + 7 < end; e += 8) {
        int2 p[8];
        #pragma unroll
        for (int j = 0; j < 8; ++j) p[j] = edges[e + j];
        unsigned sv[8];
        #pragma unroll
        for (int j = 0; j < 8; ++j) sv[j] = Su[(size_t)p[j].x * 64 + lane];
        #pragma unroll
        for (int j = 0; j < 8; ++j) {
            float w = __int_as_float(p[j].y);
            ax += w * bf2f(sv[j] & 0xFFFFu);
            ay += w * bf2f(sv[j] >> 16);
        }
    }
    for (; e < end; ++e) {
        int2 p = edges[e];
        unsigned s = Su[(size_t)p.x * 64 + lane];
        float w = __int_as_float(p.y);
        ax += w * bf2f(s & 0xFFFFu);
        ay += w * bf2f(s >> 16);
    }

    float2 o; o.x = ax; o.y = ay;
    ((float2*)(out + (size_t)node * D))[lane] = o;
}

// ---------------------------------------------------------------------------
// Fallback path (ws too small / too many buckets): fp32 S + output atomics.
// ---------------------------------------------------------------------------
__global__ __launch_bounds__(256) void gemm_f32_kernel(const float* __restrict__ X,
                                                       const float* __restrict__ W,
                                                       float* __restrict__ S,
                                                       int n_rows) {
    __shared__ float Ws[D * D];
    __shared__ float Xs[64 * 132];
    const int tid  = threadIdx.x;
    const int row0 = blockIdx.x * 64;
    #pragma unroll
    for (int i = 0; i < 16; ++i) {
        int idx = tid + i * 256;
        ((float4*)Ws)[idx] = ((const float4*)W)[idx];
    }
    #pragma unroll
    for (int i = 0; i < 8; ++i) {
        int idx = tid + i * 256;
        int r = idx >> 5, c4 = idx & 31;
        if (row0 + r < n_rows) {
            float4 v = ((const float4*)(X + (size_t)(row0 + r) * D))[c4];
            *((float4*)&Xs[r * 132 + c4 * 4]) = v;
        }
    }
    __syncthreads();
    const int cg = tid & 15, rg = tid >> 4;
    const int r0 = rg * 4, c0 = cg * 4, c1 = 64 + cg * 4;
    float acc[4][8];
    #pragma unroll
    for (int r = 0; r < 4; ++r)
        #pragma unroll
        for (int c = 0; c < 8; ++c) acc[r][c] = 0.f;
    #pragma unroll 4
    for (int k = 0; k < D; ++k) {
        float4 w0 = *((const float4*)&Ws[k * D + c0]);
        float4 w1 = *((const float4*)&Ws[k * D + c1]);
        #pragma unroll
        for (int r = 0; r < 4; ++r) {
            float x = Xs[(r0 + r) * 132 + k];
            acc[r][0] += x * w0.x; acc[r][1] += x * w0.y;
            acc[r][2] += x * w0.z; acc[r][3] += x * w0.w;
            acc[r][4] += x * w1.x; acc[r][5] += x * w1.y;
            acc[r][6] += x * w1.z; acc[r][7] += x * w1.w;
        }
    }
    #pragma unroll
    for (int r = 0; r < 4; ++r) {
        int row = row0 + r0 + r;
        if (row < n_rows) {
            float4 o0 = {acc[r][0], acc[r][1], acc[r][2], acc[r][3]};
            float4 o1 = {acc[r][4], acc[r][5], acc[r][6], acc[r][7]};
            ((float4*)(S + (size_t)row * D))[cg]      = o0;
            ((float4*)(S + (size_t)row * D))[16 + cg] = o1;
        }
    }
}

__global__ __launch_bounds__(256) void init_out_kernel(float* __restrict__ out,
                                                       const float* __restrict__ bias,
                                                       int total4) {
    int idx = blockIdx.x * blockDim.x + threadIdx.x;
    int stride = gridDim.x * blockDim.x;
    for (; idx < total4; idx += stride) {
        float4 b = ((const float4*)bias)[idx & 31];
        ((float4*)out)[idx] = b;
    }
}

__global__ __launch_bounds__(256) void spmm_atomic_kernel(const float* __restrict__ S,
                                                          const int* __restrict__ erow,
                                                          const int* __restrict__ ecol,
                                                          const float* __restrict__ ew,
                                                          float* __restrict__ out,
                                                          int n_edges) {
    const int lane   = threadIdx.x & 63;
    const int wave   = blockIdx.x * (blockDim.x >> 6) + (threadIdx.x >> 6);
    const int nwaves = gridDim.x * (blockDim.x >> 6);
    for (int e = wave; e < n_edges; e += nwaves) {
        int   col = ecol[e];
        int   row = erow[e];
        float w   = ew[e];
        float2 s  = *(((const float2*)(S + (size_t)col * D)) + lane);
        float* op = out + (size_t)row * D + lane * 2;
        unsafeAtomicAdd(op,     w * s.x);
        unsafeAtomicAdd(op + 1, w * s.y);
    }
}

extern "C" void kernel_launch(void* const* d_in, const int* in_sizes, int n_in,
                              void* d_out, int out_size, void* d_ws, size_t ws_size,
                              hipStream_t stream) {
    const float* X    = (const float*)d_in[0];
    const int*   erow = (const int*)  d_in[1];
    const int*   ecol = (const int*)  d_in[2];
    const float* ew   = (const float*)d_in[3];
    const float* W    = (const float*)d_in[4];
    const float* bias = (const float*)d_in[5];
    float* out = (float*)d_out;

    const int n_nodes = in_sizes[0] / D;
    const int n_edges = in_sizes[1];
    const int nb      = (n_nodes + BROWS - 1) / BROWS;   // 782

    // workspace: Sb (bf16) | cnt | bstart | curm | offs | binned
    size_t sb_bytes   = (size_t)n_nodes * D * sizeof(unsigned short); // 25.6 MB
    size_t cnt_bytes  = ((size_t)nb * sizeof(int) + 15) & ~(size_t)15;
    size_t offs_bytes = ((size_t)n_nodes * sizeof(int) + 15) & ~(size_t)15;
    size_t bin_bytes  = (size_t)n_edges * sizeof(int2);               // 25.6 MB
    size_t need = sb_bytes + 3 * cnt_bytes + offs_bytes + bin_bytes + 64;
    bool aux_ok = (size_t)out_size * sizeof(float) >= bin_bytes;

    if (ws_size >= need && nb <= 1024 && aux_ok) {
        char* p = (char*)d_ws;
        unsigned short* Sb = (unsigned short*)p;  p += sb_bytes;
        int* cnt    = (int*)p;                    p += cnt_bytes;
        int* bstart = (int*)p;                    p += cnt_bytes;
        int* curm   = (int*)p;                    p += cnt_bytes;
        int* offs   = (int*)p;                    p += offs_bytes;
        p = (char*)(((uintptr_t)p + 15) & ~(uintptr_t)15);
        int2* binned = (int2*)p;

        const int gemm_blocks = (n_nodes + 63) / 64;
        const int bin_blocks  = (n_edges + BIN_CHUNK - 1) / BIN_CHUNK;

        hipMemsetAsync(cnt, 0, (size_t)nb * sizeof(int), stream);
        bhist_kernel<<<256, 256, 0, stream>>>(erow, cnt, n_edges, nb);
        bscan_kernel<<<1, 1024, 0, stream>>>(cnt, bstart, curm, nb);
        gemm_bin_kernel<<<gemm_blocks + bin_blocks, 256, 0, stream>>>(
            X, W, Sb, n_nodes, erow, ecol, ew, curm, binned, n_edges, nb,
            gemm_blocks);
        csr_sort_kernel<<<nb, 512, 0, stream>>>(cnt, bstart, binned, (int2*)out,
                                                offs, n_nodes);
        spmm_csr_kernel<<<(n_nodes + 3) / 4, 256, 0, stream>>>(Sb, offs, binned, bias,
                                                               out, n_nodes, n_edges);
    } else {
        float* S = (float*)d_ws;
        gemm_f32_kernel<<<(n_nodes + 63) / 64, 256, 0, stream>>>(X, W, S, n_nodes);
        init_out_kernel<<<2048, 256, 0, stream>>>(out, bias, n_nodes * (D / 4));
        spmm_atomic_kernel<<<2048, 256, 0, stream>>>(S, erow, ecol, ew, out, n_edges);
    }
}

// Round 13
// 224.437 us; speedup vs baseline: 1.1190x; 1.0927x over previous
//
#include <hip/hip_runtime.h>
#include <hip/hip_bf16.h>

#define D 128            // D_IN == D_OUT == 128
#define BROWS 128        // nodes per coarse bucket
#define BSHIFT 7         // log2(BROWS)
#define BIN_CHUNK 16384  // edges per binning block (512 threads)
#define SORT_CAP 6144    // max edges sorted in LDS (mean ~4092, sigma ~64)

typedef __attribute__((ext_vector_type(8))) short short8;   // 8 bf16 (4 VGPR)
typedef __attribute__((ext_vector_type(4))) float f32x4;    // MFMA acc

static __device__ inline unsigned short f2bf(float x) {
    unsigned int u = __float_as_uint(x);
    return (unsigned short)((u + 0x7FFFu + ((u >> 16) & 1u)) >> 16);  // RNE
}
static __device__ inline float bf2f(unsigned int h16) {
    return __uint_as_float(h16 << 16);
}

// ---------------------------------------------------------------------------
// S = X @ W via v_mfma_f32_16x16x32_bf16 (verified R7-R11). 64x128 tile,
// K=128 one LDS pass; 16B-XOR swizzled Xs/Wt; epilogue via LDS bounce.
// Standalone dispatch (R11's grid-partition fusion starved the bin blocks).
// ---------------------------------------------------------------------------
__global__ __launch_bounds__(256) void gemm_mfma_kernel(const float* __restrict__ X,
                                                        const float* __restrict__ W,
                                                        unsigned short* __restrict__ Sb,
                                                        int n_rows) {
    __shared__ unsigned char smem[49152];   // [0,16K)=Xs / C-stage, [16K,48K)=Wt

    const int tid  = threadIdx.x;
    const int row0 = blockIdx.x * 64;

    #pragma unroll
    for (int i = 0; i < 8; ++i) {
        int idx = tid + i * 256;            // 2048 float4 units
        int r = idx >> 5, c4 = idx & 31;
        float4 v = make_float4(0.f, 0.f, 0.f, 0.f);
        if (row0 + r < n_rows) v = ((const float4*)(X + (size_t)(row0 + r) * D))[c4];
        uint2 pk;
        pk.x = (unsigned)f2bf(v.x) | ((unsigned)f2bf(v.y) << 16);
        pk.y = (unsigned)f2bf(v.z) | ((unsigned)f2bf(v.w) << 16);
        *(uint2*)(smem + r * 256 + ((c4 * 8) ^ ((r & 7) << 4))) = pk;
    }
    #pragma unroll
    for (int i = 0; i < 8; ++i) {
        int id = tid + i * 256;             // 2048 tasks: (n, 8-k chunk)
        int n = id & 127, kc = id >> 7;     // kc in [0,16)
        float f0 = W[(size_t)(kc * 8 + 0) * D + n];
        float f1 = W[(size_t)(kc * 8 + 1) * D + n];
        float f2 = W[(size_t)(kc * 8 + 2) * D + n];
        float f3 = W[(size_t)(kc * 8 + 3) * D + n];
        float f4 = W[(size_t)(kc * 8 + 4) * D + n];
        float f5 = W[(size_t)(kc * 8 + 5) * D + n];
        float f6 = W[(size_t)(kc * 8 + 6) * D + n];
        float f7 = W[(size_t)(kc * 8 + 7) * D + n];
        unsigned pk0 = (unsigned)f2bf(f0) | ((unsigned)f2bf(f1) << 16);
        unsigned pk1 = (unsigned)f2bf(f2) | ((unsigned)f2bf(f3) << 16);
        unsigned pk2 = (unsigned)f2bf(f4) | ((unsigned)f2bf(f5) << 16);
        unsigned pk3 = (unsigned)f2bf(f6) | ((unsigned)f2bf(f7) << 16);
        *(uint4*)(smem + 16384 + n * 256 + ((kc * 16) ^ ((n & 7) << 4))) =
            make_uint4(pk0, pk1, pk2, pk3);
    }
    __syncthreads();

    const int wv  = __builtin_amdgcn_readfirstlane(tid >> 6);
    const int l15 = tid & 15;
    const int lhi = (tid & 63) >> 4;

    f32x4 acc[4][2];
    #pragma unroll
    for (int m = 0; m < 4; ++m)
        #pragma unroll
        for (int j = 0; j < 2; ++j) acc[m][j] = (f32x4){0.f, 0.f, 0.f, 0.f};

    #pragma unroll
    for (int ks = 0; ks < 4; ++ks) {        // K = 4 x 32
        const int kb = ks * 64 + lhi * 16;
        short8 a[4], b[2];
        #pragma unroll
        for (int m = 0; m < 4; ++m) {
            int r = m * 16 + l15;
            a[m] = *(const short8*)(smem + r * 256 + (kb ^ ((r & 7) << 4)));
        }
        #pragma unroll
        for (int j = 0; j < 2; ++j) {
            int n = wv * 32 + j * 16 + l15;
            b[j] = *(const short8*)(smem + 16384 + n * 256 + (kb ^ ((n & 7) << 4)));
        }
        #pragma unroll
        for (int m = 0; m < 4; ++m)
            #pragma unroll
            for (int j = 0; j < 2; ++j)
                acc[m][j] = __builtin_amdgcn_mfma_f32_16x16x32_bf16(a[m], b[j],
                                                                   acc[m][j], 0, 0, 0);
    }
    __syncthreads();

    #pragma unroll
    for (int m = 0; m < 4; ++m)
        #pragma unroll
        for (int j = 0; j < 2; ++j)
            #pragma unroll
            for (int r = 0; r < 4; ++r) {
                int row = m * 16 + lhi * 4 + r;
                int col = wv * 32 + j * 16 + l15;
                *(unsigned short*)(smem + row * 256 + ((col * 2) ^ ((row & 7) << 4))) =
                    f2bf(acc[m][j][r]);
            }
    __syncthreads();
    // 64x128 bf16 tile = 1024 sixteen-byte units -> exactly 4 iterations.
    #pragma unroll
    for (int i = 0; i < 4; ++i) {
        int idx = tid + i * 256;            // 0..1023
        int r = idx >> 4, kb = (idx & 15) * 16;
        uint4 v = *(const uint4*)(smem + r * 256 + (kb ^ ((r & 7) << 4)));
        int row = row0 + r;
        if (row < n_rows)
            *(uint4*)((unsigned char*)Sb + (size_t)row * 256 + kb) = v;
    }
}

// ---------------------------------------------------------------------------
// Coarse bucket histogram: LDS-aggregated, one global atomic per bucket/block.
// ---------------------------------------------------------------------------
__global__ __launch_bounds__(256) void bhist_kernel(const int* __restrict__ erow,
                                                    int* __restrict__ cnt,
                                                    int n_edges, int nb) {
    __shared__ int h[1024];
    for (int i = threadIdx.x; i < nb; i += 256) h[i] = 0;
    __syncthreads();
    int i = blockIdx.x * blockDim.x + threadIdx.x;
    int stride = gridDim.x * blockDim.x;
    for (; i < n_edges; i += stride) atomicAdd(&h[erow[i] >> BSHIFT], 1);
    __syncthreads();
    for (int b = threadIdx.x; b < nb; b += 256)
        if (h[b]) atomicAdd(&cnt[b], h[b]);
}

// single block: exclusive scan of cnt -> bstart (stable) and curm (cursors)
__global__ __launch_bounds__(1024) void bscan_kernel(const int* __restrict__ cnt,
                                                     int* __restrict__ bstart,
                                                     int* __restrict__ curm, int nb) {
    __shared__ int s[1024];
    int tid = threadIdx.x;
    int v = (tid < nb) ? cnt[tid] : 0;
    s[tid] = v;
    __syncthreads();
    for (int d = 1; d < 1024; d <<= 1) {
        int t = (tid >= d) ? s[tid - d] : 0;
        __syncthreads();
        s[tid] += t;
        __syncthreads();
    }
    if (tid < nb) {
        int e = s[tid] - v;   // exclusive
        bstart[tid] = e;
        curm[tid]   = e;
    }
}

// ---------------------------------------------------------------------------
// Binning (standalone, 512 threads — R9's measured-good config): reserve one
// contiguous range per (block,bucket), write densely.
// Packed edge: x = (localrow<<25) | col, y = weight bits.
// ---------------------------------------------------------------------------
__global__ __launch_bounds__(512) void bin_kernel(const int* __restrict__ erow,
                                                  const int* __restrict__ ecol,
                                                  const float* __restrict__ ew,
                                                  int* __restrict__ curm,
                                                  int2* __restrict__ binned,
                                                  int n_edges, int nb) {
    __shared__ int h[1024];
    __shared__ int base[1024];
    const int c0  = blockIdx.x * BIN_CHUNK;
    const int tid = threadIdx.x;
    for (int i = tid; i < nb; i += 512) h[i] = 0;
    __syncthreads();
    for (int k = 0; k < BIN_CHUNK; k += 512) {
        int e = c0 + k + tid;
        if (e < n_edges) atomicAdd(&h[erow[e] >> BSHIFT], 1);
    }
    __syncthreads();
    for (int b = tid; b < nb; b += 512) {
        int c = h[b];
        if (c) base[b] = atomicAdd(&curm[b], c);
        h[b] = 0;   // reuse as local cursor
    }
    __syncthreads();
    for (int k = 0; k < BIN_CHUNK; k += 512) {
        int e = c0 + k + tid;
        if (e < n_edges) {
            int row = erow[e];
            int b = row >> BSHIFT;
            int pos = base[b] + atomicAdd(&h[b], 1);
            int2 p;
            p.x = (int)(((unsigned)(row & (BROWS - 1)) << 25) | (unsigned)ecol[e]);
            p.y = __float_as_int(ew[e]);
            binned[pos] = p;
        }
    }
}

// ---------------------------------------------------------------------------
// Per-bucket counting sort, 2-pass, 512 threads (LDS caps 3 blocks/CU either
// way; 512thr doubles waves/CU 12->24 vs 256). Pass 1 reads binned once
// (LDS stage + hist); scan; pass 2 scatters LDS->final global slot.
// Emits per-node offsets. Overflow (>SORT_CAP) bounces via aux (= d_out).
// ---------------------------------------------------------------------------
__global__ __launch_bounds__(512) void csr_sort_kernel(const int* __restrict__ cnt,
                                                       const int* __restrict__ bstart,
                                                       int2* __restrict__ binned,
                                                       int2* __restrict__ aux,
                                                       int* __restrict__ offs,
                                                       int n_nodes) {
    __shared__ int  lhist[BROWS];
    __shared__ int  lscan[BROWS];
    __shared__ int  lcur[BROWS];
    __shared__ int2 staged[SORT_CAP];   // 48 KB

    const int b    = blockIdx.x;
    const int bs   = bstart[b];
    const int cb   = cnt[b];
    const int row0 = b * BROWS;
    const int tid  = threadIdx.x;

    if (tid < BROWS) lhist[tid] = 0;
    __syncthreads();

    if (cb <= SORT_CAP) {
        // pass 1: single global read -> LDS stage + LDS hist
        for (int i = tid; i < cb; i += 512) {
            int2 p = binned[bs + i];
            staged[i] = p;
            atomicAdd(&lhist[(unsigned)p.x >> 25], 1);
        }
        __syncthreads();
        // inclusive Hillis-Steele scan over 128 bins
        if (tid < BROWS) lscan[tid] = lhist[tid];
        __syncthreads();
        for (int d = 1; d < BROWS; d <<= 1) {
            int t = 0;
            if (tid < BROWS && tid >= d) t = lscan[tid - d];
            __syncthreads();
            if (tid < BROWS) lscan[tid] += t;
            __syncthreads();
        }
        if (tid < BROWS) {
            int excl = lscan[tid] - lhist[tid];
            lcur[tid] = excl;
            if (row0 + tid < n_nodes) offs[row0 + tid] = bs + excl;
        }
        __syncthreads();
        // pass 2: LDS -> final global position (writes stay within ~32KB)
        for (int i = tid; i < cb; i += 512) {
            int2 p = staged[i];
            int pos = atomicAdd(&lcur[(unsigned)p.x >> 25], 1);
            binned[bs + pos] = make_int2(p.x & 0x1FFFFFF, p.y);
        }
    } else {
        // rare overflow path: 3 global passes via aux
        for (int i = tid; i < cb; i += 512)
            atomicAdd(&lhist[(unsigned)binned[bs + i].x >> 25], 1);
        __syncthreads();
        if (tid < BROWS) lscan[tid] = lhist[tid];
        __syncthreads();
        for (int d = 1; d < BROWS; d <<= 1) {
            int t = 0;
            if (tid < BROWS && tid >= d) t = lscan[tid - d];
            __syncthreads();
            if (tid < BROWS) lscan[tid] += t;
            __syncthreads();
        }
        if (tid < BROWS) {
            int excl = lscan[tid] - lhist[tid];
            lcur[tid] = excl;
            if (row0 + tid < n_nodes) offs[row0 + tid] = bs + excl;
        }
        __syncthreads();
        for (int i = tid; i < cb; i += 512) aux[bs + i] = binned[bs + i];
        __syncthreads();
        for (int i = tid; i < cb; i += 512) {
            int2 p = aux[bs + i];
            int pos = atomicAdd(&lcur[(unsigned)p.x >> 25], 1);
            binned[bs + pos] = make_int2(p.x & 0x1FFFFFF, p.y);
        }
    }
}

// ---------------------------------------------------------------------------
// CSR SpMM (R9's 107us @ 74% occ, unchanged): one wave per node;
// wave-uniform edge stream; lane l gathers bf16x2 at cols 2l,2l+1;
// 8-deep unroll; bias fused; no atomics.
// ---------------------------------------------------------------------------
__global__ __launch_bounds__(256) void spmm_csr_kernel(const unsigned short* __restrict__ Sb,
                                                       const int* __restrict__ offs,
                                                       const int2* __restrict__ edges,
                                                       const float* __restrict__ bias,
                                                       float* __restrict__ out,
                                                       int n_nodes, int n_edges) {
    const int wv   = __builtin_amdgcn_readfirstlane(threadIdx.x >> 6);
    const int node = blockIdx.x * 4 + wv;
    const int lane = threadIdx.x & 63;
    if (node >= n_nodes) return;
    const int start = offs[node];
    const int end   = (node + 1 < n_nodes) ? offs[node + 1] : n_edges;

    const unsigned* Su = (const unsigned*)Sb;   // 64 dwords per row
    float2 b2 = ((const float2*)bias)[lane];
    float ax = b2.x, ay = b2.y;

    int e = start;
    for (; e + 7 < end; e += 8) {
        int2 p[8];
        #pragma unroll
        for (int j = 0; j < 8; ++j) p[j] = edges[e + j];
        unsigned sv[8];
        #pragma unroll
        for (int j = 0; j < 8; ++j) sv[j] = Su[(size_t)p[j].x * 64 + lane];
        #pragma unroll
        for (int j = 0; j < 8; ++j) {
            float w = __int_as_float(p[j].y);
            ax += w * bf2f(sv[j] & 0xFFFFu);
            ay += w * bf2f(sv[j] >> 16);
        }
    }
    for (; e < end; ++e) {
        int2 p = edges[e];
        unsigned s = Su[(size_t)p.x * 64 + lane];
        float w = __int_as_float(p.y);
        ax += w * bf2f(s & 0xFFFFu);
        ay += w * bf2f(s >> 16);
    }

    float2 o; o.x = ax; o.y = ay;
    ((float2*)(out + (size_t)node * D))[lane] = o;
}

// ---------------------------------------------------------------------------
// Fallback path (ws too small / too many buckets): fp32 S + output atomics.
// ---------------------------------------------------------------------------
__global__ __launch_bounds__(256) void gemm_f32_kernel(const float* __restrict__ X,
                                                       const float* __restrict__ W,
                                                       float* __restrict__ S,
                                                       int n_rows) {
    __shared__ float Ws[D * D];
    __shared__ float Xs[64 * 132];
    const int tid  = threadIdx.x;
    const int row0 = blockIdx.x * 64;
    #pragma unroll
    for (int i = 0; i < 16; ++i) {
        int idx = tid + i * 256;
        ((float4*)Ws)[idx] = ((const float4*)W)[idx];
    }
    #pragma unroll
    for (int i = 0; i < 8; ++i) {
        int idx = tid + i * 256;
        int r = idx >> 5, c4 = idx & 31;
        if (row0 + r < n_rows) {
            float4 v = ((const float4*)(X + (size_t)(row0 + r) * D))[c4];
            *((float4*)&Xs[r * 132 + c4 * 4]) = v;
        }
    }
    __syncthreads();
    const int cg = tid & 15, rg = tid >> 4;
    const int r0 = rg * 4, c0 = cg * 4, c1 = 64 + cg * 4;
    float acc[4][8];
    #pragma unroll
    for (int r = 0; r < 4; ++r)
        #pragma unroll
        for (int c = 0; c < 8; ++c) acc[r][c] = 0.f;
    #pragma unroll 4
    for (int k = 0; k < D; ++k) {
        float4 w0 = *((const float4*)&Ws[k * D + c0]);
        float4 w1 = *((const float4*)&Ws[k * D + c1]);
        #pragma unroll
        for (int r = 0; r < 4; ++r) {
            float x = Xs[(r0 + r) * 132 + k];
            acc[r][0] += x * w0.x; acc[r][1] += x * w0.y;
            acc[r][2] += x * w0.z; acc[r][3] += x * w0.w;
            acc[r][4] += x * w1.x; acc[r][5] += x * w1.y;
            acc[r][6] += x * w1.z; acc[r][7] += x * w1.w;
        }
    }
    #pragma unroll
    for (int r = 0; r < 4; ++r) {
        int row = row0 + r0 + r;
        if (row < n_rows) {
            float4 o0 = {acc[r][0], acc[r][1], acc[r][2], acc[r][3]};
            float4 o1 = {acc[r][4], acc[r][5], acc[r][6], acc[r][7]};
            ((float4*)(S + (size_t)row * D))[cg]      = o0;
            ((float4*)(S + (size_t)row * D))[16 + cg] = o1;
        }
    }
}

__global__ __launch_bounds__(256) void init_out_kernel(float* __restrict__ out,
                                                       const float* __restrict__ bias,
                                                       int total4) {
    int idx = blockIdx.x * blockDim.x + threadIdx.x;
    int stride = gridDim.x * blockDim.x;
    for (; idx < total4; idx += stride) {
        float4 b = ((const float4*)bias)[idx & 31];
        ((float4*)out)[idx] = b;
    }
}

__global__ __launch_bounds__(256) void spmm_atomic_kernel(const float* __restrict__ S,
                                                          const int* __restrict__ erow,
                                                          const int* __restrict__ ecol,
                                                          const float* __restrict__ ew,
                                                          float* __restrict__ out,
                                                          int n_edges) {
    const int lane   = threadIdx.x & 63;
    const int wave   = blockIdx.x * (blockDim.x >> 6) + (threadIdx.x >> 6);
    const int nwaves = gridDim.x * (blockDim.x >> 6);
    for (int e = wave; e < n_edges; e += nwaves) {
        int   col = ecol[e];
        int   row = erow[e];
        float w   = ew[e];
        float2 s  = *(((const float2*)(S + (size_t)col * D)) + lane);
        float* op = out + (size_t)row * D + lane * 2;
        unsafeAtomicAdd(op,     w * s.x);
        unsafeAtomicAdd(op + 1, w * s.y);
    }
}

extern "C" void kernel_launch(void* const* d_in, const int* in_sizes, int n_in,
                              void* d_out, int out_size, void* d_ws, size_t ws_size,
                              hipStream_t stream) {
    const float* X    = (const float*)d_in[0];
    const int*   erow = (const int*)  d_in[1];
    const int*   ecol = (const int*)  d_in[2];
    const float* ew   = (const float*)d_in[3];
    const float* W    = (const float*)d_in[4];
    const float* bias = (const float*)d_in[5];
    float* out = (float*)d_out;

    const int n_nodes = in_sizes[0] / D;
    const int n_edges = in_sizes[1];
    const int nb      = (n_nodes + BROWS - 1) / BROWS;   // 782

    // workspace: Sb (bf16) | cnt | bstart | curm | offs | binned
    size_t sb_bytes   = (size_t)n_nodes * D * sizeof(unsigned short); // 25.6 MB
    size_t cnt_bytes  = ((size_t)nb * sizeof(int) + 15) & ~(size_t)15;
    size_t offs_bytes = ((size_t)n_nodes * sizeof(int) + 15) & ~(size_t)15;
    size_t bin_bytes  = (size_t)n_edges * sizeof(int2);               // 25.6 MB
    size_t need = sb_bytes + 3 * cnt_bytes + offs_bytes + bin_bytes + 64;
    bool aux_ok = (size_t)out_size * sizeof(float) >= bin_bytes;

    if (ws_size >= need && nb <= 1024 && aux_ok) {
        char* p = (char*)d_ws;
        unsigned short* Sb = (unsigned short*)p;  p += sb_bytes;
        int* cnt    = (int*)p;                    p += cnt_bytes;
        int* bstart = (int*)p;                    p += cnt_bytes;
        int* curm   = (int*)p;                    p += cnt_bytes;
        int* offs   = (int*)p;                    p += offs_bytes;
        p = (char*)(((uintptr_t)p + 15) & ~(uintptr_t)15);
        int2* binned = (int2*)p;

        gemm_mfma_kernel<<<(n_nodes + 63) / 64, 256, 0, stream>>>(X, W, Sb, n_nodes);
        hipMemsetAsync(cnt, 0, (size_t)nb * sizeof(int), stream);
        bhist_kernel<<<256, 256, 0, stream>>>(erow, cnt, n_edges, nb);
        bscan_kernel<<<1, 1024, 0, stream>>>(cnt, bstart, curm, nb);
        bin_kernel<<<(n_edges + BIN_CHUNK - 1) / BIN_CHUNK, 512, 0, stream>>>(
            erow, ecol, ew, curm, binned, n_edges, nb);
        csr_sort_kernel<<<nb, 512, 0, stream>>>(cnt, bstart, binned, (int2*)out,
                                                offs, n_nodes);
        spmm_csr_kernel<<<(n_nodes + 3) / 4, 256, 0, stream>>>(Sb, offs, binned, bias,
                                                               out, n_nodes, n_edges);
    } else {
        float* S = (float*)d_ws;
        gemm_f32_kernel<<<(n_nodes + 63) / 64, 256, 0, stream>>>(X, W, S, n_nodes);
        init_out_kernel<<<2048, 256, 0, stream>>>(out, bias, n_nodes * (D / 4));
        spmm_atomic_kernel<<<2048, 256, 0, stream>>>(S, erow, ecol, ew, out, n_edges);
    }
}